// Round 14
// baseline (294.058 us; speedup 1.0000x reference)
//
#include <hip/hip_runtime.h>
#include <hip/hip_fp16.h>
#include <hip/hip_cooperative_groups.h>
#include <math.h>

namespace cg = cooperative_groups;

#define NN 100000
#define NE 1600000
#define D 64
#define BSH 8                         // bin = dst >> 8  (256 nodes/bin)
#define NBIN 391                      // ceil(100000/256)
#define EB 8192                       // edges per binning block
#define NBB ((NE + EB - 1) / EB)      // 196

typedef _Float16 f16x8 __attribute__((ext_vector_type(8)));
typedef float f32x4 __attribute__((ext_vector_type(4)));
typedef int   i32x4 __attribute__((ext_vector_type(4)));
typedef float fl32x4 __attribute__((ext_vector_type(4)));

__device__ __forceinline__ int2 ldnt2(const int2* p) {
    unsigned long long r = __builtin_nontemporal_load((const unsigned long long*)p);
    int2 o;
    o.x = (int)(unsigned)(r & 0xffffffffu);
    o.y = (int)(unsigned)(r >> 32);
    return o;
}

// ---------------- fused CSR build (cooperative): hist -> scan -> scatter -> deg+csr ----
__global__ void k_csrbuild(const int* __restrict__ src, const int* __restrict__ dst,
                           const float* __restrict__ w, int* __restrict__ counts,
                           int* __restrict__ binStart, int2* __restrict__ binned,
                           float* __restrict__ dinv, int* __restrict__ row_ptr,
                           int2* __restrict__ edges, int E, int n) {
    cg::grid_group grid = cg::this_grid();
    __shared__ int lds[1280];
    int bid = blockIdx.x, t = threadIdx.x;
    int e0 = bid * EB;
    int e1 = min(e0 + EB, E);

    // ---- phase A: per-block bin histogram (LDS atomics) ----
    for (int i = t; i < NBIN; i += 256) lds[i] = 0;
    __syncthreads();
    for (int e = e0 + t * 4; e < e1; e += 256 * 4) {
        i32x4 d4 = __builtin_nontemporal_load((const i32x4*)(dst + e));
        atomicAdd(&lds[d4.x >> BSH], 1);
        atomicAdd(&lds[d4.y >> BSH], 1);
        atomicAdd(&lds[d4.z >> BSH], 1);
        atomicAdd(&lds[d4.w >> BSH], 1);
    }
    __syncthreads();
    for (int i = t; i < NBIN; i += 256) counts[bid * NBIN + i] = lds[i];
    grid.sync();

    // ---- phase B: block 0 scans (per-bin block prefixes + bin bases) ----
    if (bid == 0) {
        lds[t] = 0; lds[t + 256] = 0;
        __syncthreads();
        for (int b = t; b < NBIN; b += 256) {
            int sum = 0;
            for (int k = 0; k < NBB; k++) {
                int idx = k * NBIN + b;          // coalesced across b
                int c = counts[idx];
                counts[idx] = sum;               // exclusive per-block prefix
                sum += c;
            }
            lds[b] = sum;                        // bin total
        }
        __syncthreads();
        if (t < 64) {                            // wave scan of 391 totals
            int lane = t, carry = 0;
            for (int base = 0; base < NBIN; base += 64) {
                int idx = base + lane;
                int orig = (idx < NBIN) ? lds[idx] : 0;
                int v = orig;
#pragma unroll
                for (int o = 1; o < 64; o <<= 1) {
                    int u = __shfl_up(v, o);
                    if (lane >= o) v += u;
                }
                if (idx < NBIN) binStart[idx] = carry + v - orig;   // exclusive
                carry += __shfl(v, 63);
            }
            if (lane == 0) binStart[NBIN] = carry;
        }
    }
    grid.sync();

    // ---- phase C: scatter edges into bin-contiguous order ----
    for (int i = t; i < NBIN; i += 256)
        lds[i] = binStart[i] + counts[bid * NBIN + i];
    __syncthreads();
    for (int e = e0 + t * 4; e < e1; e += 256 * 4) {
        i32x4  d4 = __builtin_nontemporal_load((const i32x4*)(dst + e));
        i32x4  s4 = __builtin_nontemporal_load((const i32x4*)(src + e));
        fl32x4 w4 = __builtin_nontemporal_load((const fl32x4*)(w + e));
        int pos;
        pos = atomicAdd(&lds[d4.x >> BSH], 1);
        binned[pos] = make_int2(((d4.x & 255) << 17) | s4.x, __float_as_int(w4.x));
        pos = atomicAdd(&lds[d4.y >> BSH], 1);
        binned[pos] = make_int2(((d4.y & 255) << 17) | s4.y, __float_as_int(w4.y));
        pos = atomicAdd(&lds[d4.z >> BSH], 1);
        binned[pos] = make_int2(((d4.z & 255) << 17) | s4.z, __float_as_int(w4.z));
        pos = atomicAdd(&lds[d4.w >> BSH], 1);
        binned[pos] = make_int2(((d4.w & 255) << 17) | s4.w, __float_as_int(w4.w));
    }
    grid.sync();

    // ---- phase D: per-bin deg/dinv/row_ptr + rank -> compact CSR ----
    int*   cnt = lds;
    float* ws  = (float*)(lds + 256);
    int*   off = lds + 512;
    int*   rp  = lds + 768;
    float* dd  = (float*)(lds + 1024);
    for (int b = bid; b < NBIN; b += NBB) {
        __syncthreads();
        cnt[t] = 0; ws[t] = 0.0f;
        __syncthreads();
        int be0 = binStart[b], be1 = binStart[b + 1];
        for (int e = be0 + t; e < be1; e += 256) {
            int2 r = binned[e];
            int dlow = (unsigned)r.x >> 17;
            atomicAdd(&cnt[dlow], 1);
            atomicAdd(&ws[dlow], __int_as_float(r.y));
        }
        __syncthreads();
        int v = cnt[t];
        off[t] = v;
        __syncthreads();
        for (int o = 1; o < 256; o <<= 1) {
            int add = (t >= o) ? off[t - o] : 0;
            __syncthreads();
            off[t] += add;
            __syncthreads();
        }
        int node = b * 256 + t;
        float dvv = rsqrtf(1.0f + ws[t]);        // self-loop weight 1
        rp[t] = be0 + off[t] - v;                // exclusive row base
        dd[t] = dvv;
        if (node < n) { dinv[node] = dvv; row_ptr[node] = rp[t]; }
        if (b == NBIN - 1 && t == 0) row_ptr[n] = binStart[NBIN];
        cnt[t] = 0;                              // reuse as rank cursor
        __syncthreads();
        for (int e = be0 + t; e < be1; e += 256) {  // pass 2: bin is L2-hot
            int2 r = binned[e];
            int dlow = (unsigned)r.x >> 17;
            int s = r.x & 0x1FFFF;
            int rank = atomicAdd(&cnt[dlow], 1);
            float nv = __int_as_float(r.y) * dd[dlow];   // w * dinv[dst]
            edges[rp[dlow] + rank] = make_int2(s, __float_as_int(nv));
        }
    }
}

// ---------------- dense: T' = dinv ⊙ (X @ W) via MFMA 16x16x32 f16 ----------------
// Wave computes 32 rows (2 tiles of 16). A/B frag: lane&15 = row/col,
// 8 contiguous k at (lane>>4)*8. C/D: col=lane&15, row=(lane>>4)*4+reg.
template <int IN_HALF>
__global__ void k_gemm(const void* __restrict__ Xv, const float* __restrict__ W,
                       const float* __restrict__ dinv, __half* __restrict__ T, int n) {
    int wid = (int)((blockIdx.x * blockDim.x + threadIdx.x) >> 6);
    int lane = threadIdx.x & 63;
    int col16 = lane & 15, kg = lane >> 4;
    int r0 = wid * 32;
    if (r0 >= n) return;
    // B fragments: bf[kk][ct], elem j = W[kk*32 + kg*8 + j][ct*16 + col16]
    f16x8 bf[2][4];
#pragma unroll
    for (int kk = 0; kk < 2; kk++)
#pragma unroll
        for (int ct = 0; ct < 4; ct++) {
            f16x8 b;
#pragma unroll
            for (int j = 0; j < 8; j++)
                b[j] = (_Float16)W[(size_t)(kk * 32 + kg * 8 + j) * D + ct * 16 + col16];
            bf[kk][ct] = b;
        }
#pragma unroll
    for (int tt = 0; tt < 2; tt++) {
        int row = r0 + tt * 16 + col16;           // this lane's A row
        f16x8 a0, a1;
        if (IN_HALF) {
            const _Float16* xr = (const _Float16*)Xv + (size_t)row * D;
            a0 = *(const f16x8*)(xr + kg * 8);
            a1 = *(const f16x8*)(xr + 32 + kg * 8);
        } else {
            const float* xr = (const float*)Xv + (size_t)row * D;
#pragma unroll
            for (int j = 0; j < 8; j++) {
                a0[j] = (_Float16)xr[kg * 8 + j];
                a1[j] = (_Float16)xr[32 + kg * 8 + j];
            }
        }
        float dvr[4];
#pragma unroll
        for (int r = 0; r < 4; r++) dvr[r] = dinv[r0 + tt * 16 + kg * 4 + r];
#pragma unroll
        for (int ct = 0; ct < 4; ct++) {
            f32x4 z = {0.0f, 0.0f, 0.0f, 0.0f};
            z = __builtin_amdgcn_mfma_f32_16x16x32_f16(a0, bf[0][ct], z, 0, 0, 0);
            z = __builtin_amdgcn_mfma_f32_16x16x32_f16(a1, bf[1][ct], z, 0, 0, 0);
            __half* to = T + (size_t)(r0 + tt * 16 + kg * 4) * D + ct * 16 + col16;
#pragma unroll
            for (int r = 0; r < 4; r++)
                to[(size_t)r * D] = __float2half(z[r] * dvr[r]);
        }
    }
}

// ---------------- aggregation on pre-scaled fp16 rows (round-11 proven form) --------
// out = relu(Σ ev·T'[s] + dv·T'[v] + b); optional fused @W3 (writes dv·t3).
// Tiers 16/8/4/2 edges (ILP 8/4/2/1 per half-wave) + odd tail; NT edge loads.
template <int FUSE_W3>
__global__ void k_agg(const __half2* __restrict__ T2, const int* __restrict__ row_ptr,
                      const int2* __restrict__ edges, const float* __restrict__ dinv,
                      const float* __restrict__ bias, const float* __restrict__ W3,
                      void* __restrict__ outv, int n) {
    int wave = (int)((blockIdx.x * blockDim.x + threadIdx.x) >> 6);
    int lane = threadIdx.x & 63;
    if (wave >= n) return;
    int c = lane & 31;
    int h = lane >> 5;
    int beg = row_ptr[wave], end = row_ptr[wave + 1];
    float ax = 0.0f, ay = 0.0f, bx = 0.0f, by = 0.0f;
    int i = beg;
    for (; i + 16 <= end; i += 16) {
        int2 er[8];
#pragma unroll
        for (int j = 0; j < 8; j++) er[j] = ldnt2(&edges[i + 2 * j + h]);
        __half2 tv[8];
#pragma unroll
        for (int j = 0; j < 8; j++) tv[j] = T2[(size_t)er[j].x * 32 + c];
#pragma unroll
        for (int j = 0; j < 8; j++) {
            float nv = __int_as_float(er[j].y);
            float2 f = __half22float2(tv[j]);
            if (j & 1) { bx += nv * f.x; by += nv * f.y; }
            else       { ax += nv * f.x; ay += nv * f.y; }
        }
    }
    if (i + 8 <= end) {
        int2 er[4];
#pragma unroll
        for (int j = 0; j < 4; j++) er[j] = ldnt2(&edges[i + 2 * j + h]);
        __half2 tv[4];
#pragma unroll
        for (int j = 0; j < 4; j++) tv[j] = T2[(size_t)er[j].x * 32 + c];
#pragma unroll
        for (int j = 0; j < 4; j++) {
            float nv = __int_as_float(er[j].y);
            float2 f = __half22float2(tv[j]);
            if (j & 1) { bx += nv * f.x; by += nv * f.y; }
            else       { ax += nv * f.x; ay += nv * f.y; }
        }
        i += 8;
    }
    if (i + 4 <= end) {
        int2 er[2];
#pragma unroll
        for (int j = 0; j < 2; j++) er[j] = ldnt2(&edges[i + 2 * j + h]);
#pragma unroll
        for (int j = 0; j < 2; j++) {
            float nv = __int_as_float(er[j].y);
            float2 f = __half22float2(T2[(size_t)er[j].x * 32 + c]);
            if (j & 1) { bx += nv * f.x; by += nv * f.y; }
            else       { ax += nv * f.x; ay += nv * f.y; }
        }
        i += 4;
    }
    if (i + 2 <= end) {
        int2 e = ldnt2(&edges[i + h]);
        float nv = __int_as_float(e.y);
        float2 f = __half22float2(T2[(size_t)e.x * 32 + c]);
        ax += nv * f.x; ay += nv * f.y;
        i += 2;
    }
    if (i < end && h == 0) {                       // odd leftover: half 0 only
        int2 e = ldnt2(&edges[i]);
        float nv = __int_as_float(e.y);
        float2 f = __half22float2(T2[(size_t)e.x * 32 + c]);
        ax += nv * f.x; ay += nv * f.y;
    }
    ax += bx; ay += by;
    ax += __shfl_xor(ax, 32);                      // combine halves
    ay += __shfl_xor(ay, 32);
    float dv = dinv[wave];
    float2 self = __half22float2(T2[(size_t)wave * 32 + c]);  // pre-scaled by dinv[v]
    float hx = fmaxf(ax + dv * self.x + bias[2 * c], 0.0f);
    float hy = fmaxf(ay + dv * self.y + bias[2 * c + 1], 0.0f);
    if (FUSE_W3) {
        float pp = hx * W3[2 * c] + hy * W3[2 * c + 1];
#pragma unroll
        for (int off = 16; off; off >>= 1) pp += __shfl_xor(pp, off);
        if (lane == 0) ((float*)outv)[wave] = dv * pp;   // store pre-scaled t3'
    } else {
        if (lane < 32) ((__half2*)outv)[(size_t)wave * 32 + c] = __floats2half2_rn(hx, hy);
    }
}

// ---------------- layer 3 on pre-scaled t3': sigmoid(Σ ev·t3'[s] + dv·t3'[v] + b3) ----
__global__ void k_agg3(const float* __restrict__ t3, const int* __restrict__ row_ptr,
                       const int2* __restrict__ edges, const float* __restrict__ dinv,
                       const float* __restrict__ b3, float* __restrict__ out, int n) {
    int v = blockIdx.x * blockDim.x + threadIdx.x;
    if (v >= n) return;
    float dv = dinv[v];
    float acc0 = dv * t3[v];
    float acc1 = 0.0f;
    int beg = row_ptr[v], end = row_ptr[v + 1];
    int i = beg;
    for (; i + 8 <= end; i += 8) {
        int2 er[8]; float av[8];
#pragma unroll
        for (int j = 0; j < 8; j++) er[j] = ldnt2(&edges[i + j]);
#pragma unroll
        for (int j = 0; j < 8; j++) av[j] = t3[er[j].x];
#pragma unroll
        for (int j = 0; j < 8; j++) {
            if (j & 1) acc1 += __int_as_float(er[j].y) * av[j];
            else       acc0 += __int_as_float(er[j].y) * av[j];
        }
    }
    for (; i < end; i++) {
        int2 e = ldnt2(&edges[i]);
        acc0 += __int_as_float(e.y) * t3[e.x];
    }
    float z = acc0 + acc1 + b3[0];
    out[v] = 1.0f / (1.0f + expf(-z));
}

extern "C" void kernel_launch(void* const* d_in, const int* in_sizes, int n_in,
                              void* d_out, int out_size, void* d_ws, size_t ws_size,
                              hipStream_t stream) {
    const float* x  = (const float*)d_in[0];
    const int*   ei = (const int*)d_in[1];
    const float* w  = (const float*)d_in[2];
    const float* W1 = (const float*)d_in[3];
    const float* b1 = (const float*)d_in[4];
    const float* W2 = (const float*)d_in[5];
    const float* b2 = (const float*)d_in[6];
    const float* W3 = (const float*)d_in[7];
    const float* b3 = (const float*)d_in[8];
    float* out = (float*)d_out;

    int N = NN, E = NE;
    const int* src = ei;
    const int* dst = ei + E;

    // workspace carve (256B aligned)
    char* p = (char*)d_ws;
    auto alloc = [&](size_t bytes) -> char* {
        char* r = p;
        p += (bytes + 255) & ~(size_t)255;
        return r;
    };
    float* dinv    = (float*)alloc((size_t)N * 4);
    int*   row_ptr = (int*)alloc((size_t)(N + 1) * 4);
    int*   binStart= (int*)alloc((NBIN + 1) * 4);
    int*   counts  = (int*)alloc((size_t)NBB * NBIN * 4);
    int2*  binned  = (int2*)alloc((size_t)E * 8);       // bin-ordered records
    int2*  edges   = (int2*)alloc((size_t)E * 8);       // compact CSR (src, w*dinv[dst])
    __half* bufA   = (__half*)alloc((size_t)N * D * 2);
    __half* bufB   = (__half*)alloc((size_t)N * D * 2);
    float* t3      = (float*)alloc((size_t)N * 4);

    const int BT = 256;
    int gN = (N + BT - 1) / BT;
    int gW = (N * 64 + BT - 1) / BT;               // wave-per-node grids (4 waves/block)
    int nWaves = (N + 31) / 32;                    // gemm: wave per 32 rows
    int gG = (nWaves * 64 + BT - 1) / BT;

    // --- CSR build: one cooperative kernel, zero global atomics ---
    void* args[] = {(void*)&src, (void*)&dst, (void*)&w, (void*)&counts, (void*)&binStart,
                    (void*)&binned, (void*)&dinv, (void*)&row_ptr, (void*)&edges,
                    (void*)&E, (void*)&N};
    hipLaunchCooperativeKernel((void*)k_csrbuild, dim3(NBB), dim3(BT), args, 0, stream);

    // --- layer 1 ---
    k_gemm<0><<<gG, BT, 0, stream>>>(x, W1, dinv, bufA, N);
    k_agg<0><<<gW, BT, 0, stream>>>((const __half2*)bufA, row_ptr, edges, dinv, b1, nullptr, bufB, N);
    // --- layer 2 (fused h2 @ W3 epilogue -> t3') ---
    k_gemm<1><<<gG, BT, 0, stream>>>(bufB, W2, dinv, bufA, N);
    k_agg<1><<<gW, BT, 0, stream>>>((const __half2*)bufA, row_ptr, edges, dinv, b2, W3, t3, N);
    // --- layer 3: scalar aggregation + bias + sigmoid ---
    k_agg3<<<gN, BT, 0, stream>>>(t3, row_ptr, edges, dinv, b3, out, N);
}

// Round 15
// 212.324 us; speedup vs baseline: 1.3850x; 1.3850x over previous
//
#include <hip/hip_runtime.h>
#include <hip/hip_fp16.h>
#include <math.h>

#define NN 100000
#define NE 1600000
#define D 64
#define BSH 8                         // bin = dst >> 8  (256 nodes/bin)
#define NBIN 391                      // ceil(100000/256)
#define EB 8192                       // edges per binning block
#define NBB ((NE + EB - 1) / EB)      // 196

typedef _Float16 f16x8 __attribute__((ext_vector_type(8)));
typedef float f32x4 __attribute__((ext_vector_type(4)));
typedef int   i32x4 __attribute__((ext_vector_type(4)));
typedef float fl32x4 __attribute__((ext_vector_type(4)));

__device__ __forceinline__ int2 ldnt2(const int2* p) {
    unsigned long long r = __builtin_nontemporal_load((const unsigned long long*)p);
    int2 o;
    o.x = (int)(unsigned)(r & 0xffffffffu);
    o.y = (int)(unsigned)(r >> 32);
    return o;
}

// ---------------- pass A: per-block bin histogram (LDS atomics only) ----------------
__global__ void k_binhist(const int* __restrict__ dst, int* __restrict__ counts, int E) {
    __shared__ int h[NBIN];
    for (int i = threadIdx.x; i < NBIN; i += blockDim.x) h[i] = 0;
    __syncthreads();
    int e0 = blockIdx.x * EB;
    int e1 = min(e0 + EB, E);
    for (int e = e0 + (int)threadIdx.x * 4; e < e1; e += blockDim.x * 4) {
        i32x4 d4 = __builtin_nontemporal_load((const i32x4*)(dst + e));
        atomicAdd(&h[d4.x >> BSH], 1);
        atomicAdd(&h[d4.y >> BSH], 1);
        atomicAdd(&h[d4.z >> BSH], 1);
        atomicAdd(&h[d4.w >> BSH], 1);
    }
    __syncthreads();
    for (int i = threadIdx.x; i < NBIN; i += blockDim.x)
        counts[blockIdx.x * NBIN + i] = h[i];
}

// ---------------- scan: per-bin prefix over blocks + bin bases ----------------
__global__ void k_binscan(int* __restrict__ counts, int* __restrict__ binStart) {
    __shared__ int tot[512];
    int b = threadIdx.x;
    int sum = 0;
    if (b < NBIN) {
#pragma unroll 8
        for (int k = 0; k < NBB; k++) {
            int idx = k * NBIN + b;           // coalesced across b
            int c = counts[idx];
            counts[idx] = sum;                // exclusive per-block prefix
            sum += c;
        }
    }
    tot[b] = (b < NBIN) ? sum : 0;
    __syncthreads();
    int v = tot[b];
    for (int off = 1; off < 512; off <<= 1) {
        int add = (b >= off) ? tot[b - off] : 0;
        __syncthreads();
        tot[b] += add;
        __syncthreads();
    }
    if (b < NBIN) binStart[b] = tot[b] - v;   // exclusive bin base
    if (b == NBIN - 1) binStart[NBIN] = tot[b];  // == E
}

// ---------------- pass B: scatter edges into bin-contiguous order ----------------
__global__ void k_binscatter(const int* __restrict__ src, const int* __restrict__ dst,
                             const float* __restrict__ w, const int* __restrict__ counts,
                             const int* __restrict__ binStart, int2* __restrict__ binned,
                             int E) {
    __shared__ int cur[NBIN];
    for (int i = threadIdx.x; i < NBIN; i += blockDim.x)
        cur[i] = binStart[i] + counts[blockIdx.x * NBIN + i];
    __syncthreads();
    int e0 = blockIdx.x * EB;
    int e1 = min(e0 + EB, E);
    for (int e = e0 + (int)threadIdx.x * 4; e < e1; e += blockDim.x * 4) {
        i32x4  d4 = __builtin_nontemporal_load((const i32x4*)(dst + e));
        i32x4  s4 = __builtin_nontemporal_load((const i32x4*)(src + e));
        fl32x4 w4 = __builtin_nontemporal_load((const fl32x4*)(w + e));
        int pos;
        pos = atomicAdd(&cur[d4.x >> BSH], 1);
        binned[pos] = make_int2(((d4.x & 255) << 17) | s4.x, __float_as_int(w4.x));
        pos = atomicAdd(&cur[d4.y >> BSH], 1);
        binned[pos] = make_int2(((d4.y & 255) << 17) | s4.y, __float_as_int(w4.y));
        pos = atomicAdd(&cur[d4.z >> BSH], 1);
        binned[pos] = make_int2(((d4.z & 255) << 17) | s4.z, __float_as_int(w4.z));
        pos = atomicAdd(&cur[d4.w >> BSH], 1);
        binned[pos] = make_int2(((d4.w & 255) << 17) | s4.w, __float_as_int(w4.w));
    }
}

// ---------------- fused deg + CSR: dinv/row_ptr (pass 1) + rank/copy (pass 2) ------
// Edge record = (src, raw w bits): dinv factors are applied in gemm (src side)
// and in the agg epilogue (dst side, hoisted out of the row sum).
__global__ void k_degcsr(const int2* __restrict__ binned, const int* __restrict__ binStart,
                         float* __restrict__ dinv, int* __restrict__ row_ptr,
                         int2* __restrict__ edges, int n) {
    __shared__ int   cnt[256];
    __shared__ float ws[256];
    __shared__ int   off[256];
    __shared__ int   rp[256];
    int b = blockIdx.x, t = threadIdx.x;
    cnt[t] = 0; ws[t] = 0.0f;
    __syncthreads();
    int e0 = binStart[b], e1 = binStart[b + 1];
    for (int e = e0 + t; e < e1; e += 256) {
        int2 r = binned[e];
        int dlow = (unsigned)r.x >> 17;
        atomicAdd(&cnt[dlow], 1);
        atomicAdd(&ws[dlow], __int_as_float(r.y));
    }
    __syncthreads();
    int v = cnt[t];
    off[t] = v;
    __syncthreads();
    for (int o = 1; o < 256; o <<= 1) {
        int add = (t >= o) ? off[t - o] : 0;
        __syncthreads();
        off[t] += add;
        __syncthreads();
    }
    int node = b * 256 + t;
    rp[t] = e0 + off[t] - v;                 // exclusive row base
    if (node < n) {
        dinv[node] = rsqrtf(1.0f + ws[t]);   // self-loop weight 1
        row_ptr[node] = rp[t];
    }
    if (b == NBIN - 1 && t == 0) row_ptr[n] = binStart[NBIN];
    cnt[t] = 0;                              // reuse as rank cursor
    __syncthreads();
    for (int e = e0 + t; e < e1; e += 256) { // pass 2: bin is L2-hot, pure rank+copy
        int2 r = binned[e];
        int dlow = (unsigned)r.x >> 17;
        int rank = atomicAdd(&cnt[dlow], 1);
        edges[rp[dlow] + rank] = make_int2(r.x & 0x1FFFF, r.y);
    }
}

// ---------------- dense: T' = dinv ⊙ (X @ W) via MFMA 16x16x32 f16 ----------------
// Wave computes 32 rows (2 tiles of 16). A/B frag: lane&15 = row/col,
// 8 contiguous k at (lane>>4)*8. C/D: col=lane&15, row=(lane>>4)*4+reg.
template <int IN_HALF>
__global__ void k_gemm(const void* __restrict__ Xv, const float* __restrict__ W,
                       const float* __restrict__ dinv, __half* __restrict__ T, int n) {
    int wid = (int)((blockIdx.x * blockDim.x + threadIdx.x) >> 6);
    int lane = threadIdx.x & 63;
    int col16 = lane & 15, kg = lane >> 4;
    int r0 = wid * 32;
    if (r0 >= n) return;
    // B fragments: bf[kk][ct], elem j = W[kk*32 + kg*8 + j][ct*16 + col16]
    f16x8 bf[2][4];
#pragma unroll
    for (int kk = 0; kk < 2; kk++)
#pragma unroll
        for (int ct = 0; ct < 4; ct++) {
            f16x8 b;
#pragma unroll
            for (int j = 0; j < 8; j++)
                b[j] = (_Float16)W[(size_t)(kk * 32 + kg * 8 + j) * D + ct * 16 + col16];
            bf[kk][ct] = b;
        }
#pragma unroll
    for (int tt = 0; tt < 2; tt++) {
        int row = r0 + tt * 16 + col16;           // this lane's A row
        f16x8 a0, a1;
        if (IN_HALF) {
            const _Float16* xr = (const _Float16*)Xv + (size_t)row * D;
            a0 = *(const f16x8*)(xr + kg * 8);
            a1 = *(const f16x8*)(xr + 32 + kg * 8);
        } else {
            const float* xr = (const float*)Xv + (size_t)row * D;
#pragma unroll
            for (int j = 0; j < 8; j++) {
                a0[j] = (_Float16)xr[kg * 8 + j];
                a1[j] = (_Float16)xr[32 + kg * 8 + j];
            }
        }
        float dvr[4];
#pragma unroll
        for (int r = 0; r < 4; r++) dvr[r] = dinv[r0 + tt * 16 + kg * 4 + r];
#pragma unroll
        for (int ct = 0; ct < 4; ct++) {
            f32x4 z = {0.0f, 0.0f, 0.0f, 0.0f};
            z = __builtin_amdgcn_mfma_f32_16x16x32_f16(a0, bf[0][ct], z, 0, 0, 0);
            z = __builtin_amdgcn_mfma_f32_16x16x32_f16(a1, bf[1][ct], z, 0, 0, 0);
            __half* to = T + (size_t)(r0 + tt * 16 + kg * 4) * D + ct * 16 + col16;
#pragma unroll
            for (int r = 0; r < 4; r++)
                to[(size_t)r * D] = __float2half(z[r] * dvr[r]);
        }
    }
}

// ---------------- aggregation on pre-scaled fp16 rows (round-11 proven form) --------
// acc = Σ w_e·T'[s] + T'[v]  (self-loop weight 1); out = relu(dv·acc + b).
// Tiers 16/8/4/2 edges (ILP 8/4/2/1 per half-wave) + odd tail; NT edge loads.
template <int FUSE_W3>
__global__ void k_agg(const __half2* __restrict__ T2, const int* __restrict__ row_ptr,
                      const int2* __restrict__ edges, const float* __restrict__ dinv,
                      const float* __restrict__ bias, const float* __restrict__ W3,
                      void* __restrict__ outv, int n) {
    int wave = (int)((blockIdx.x * blockDim.x + threadIdx.x) >> 6);
    int lane = threadIdx.x & 63;
    if (wave >= n) return;
    int c = lane & 31;
    int h = lane >> 5;
    int beg = row_ptr[wave], end = row_ptr[wave + 1];
    float ax = 0.0f, ay = 0.0f, bx = 0.0f, by = 0.0f;
    int i = beg;
    for (; i + 16 <= end; i += 16) {
        int2 er[8];
#pragma unroll
        for (int j = 0; j < 8; j++) er[j] = ldnt2(&edges[i + 2 * j + h]);
        __half2 tv[8];
#pragma unroll
        for (int j = 0; j < 8; j++) tv[j] = T2[(size_t)er[j].x * 32 + c];
#pragma unroll
        for (int j = 0; j < 8; j++) {
            float nv = __int_as_float(er[j].y);
            float2 f = __half22float2(tv[j]);
            if (j & 1) { bx += nv * f.x; by += nv * f.y; }
            else       { ax += nv * f.x; ay += nv * f.y; }
        }
    }
    if (i + 8 <= end) {
        int2 er[4];
#pragma unroll
        for (int j = 0; j < 4; j++) er[j] = ldnt2(&edges[i + 2 * j + h]);
        __half2 tv[4];
#pragma unroll
        for (int j = 0; j < 4; j++) tv[j] = T2[(size_t)er[j].x * 32 + c];
#pragma unroll
        for (int j = 0; j < 4; j++) {
            float nv = __int_as_float(er[j].y);
            float2 f = __half22float2(tv[j]);
            if (j & 1) { bx += nv * f.x; by += nv * f.y; }
            else       { ax += nv * f.x; ay += nv * f.y; }
        }
        i += 8;
    }
    if (i + 4 <= end) {
        int2 er[2];
#pragma unroll
        for (int j = 0; j < 2; j++) er[j] = ldnt2(&edges[i + 2 * j + h]);
#pragma unroll
        for (int j = 0; j < 2; j++) {
            float nv = __int_as_float(er[j].y);
            float2 f = __half22float2(T2[(size_t)er[j].x * 32 + c]);
            if (j & 1) { bx += nv * f.x; by += nv * f.y; }
            else       { ax += nv * f.x; ay += nv * f.y; }
        }
        i += 4;
    }
    if (i + 2 <= end) {
        int2 e = ldnt2(&edges[i + h]);
        float nv = __int_as_float(e.y);
        float2 f = __half22float2(T2[(size_t)e.x * 32 + c]);
        ax += nv * f.x; ay += nv * f.y;
        i += 2;
    }
    if (i < end && h == 0) {                       // odd leftover: half 0 only
        int2 e = ldnt2(&edges[i]);
        float nv = __int_as_float(e.y);
        float2 f = __half22float2(T2[(size_t)e.x * 32 + c]);
        ax += nv * f.x; ay += nv * f.y;
    }
    ax += bx; ay += by;
    ax += __shfl_xor(ax, 32);                      // combine halves
    ay += __shfl_xor(ay, 32);
    float dv = dinv[wave];
    float2 self = __half22float2(T2[(size_t)wave * 32 + c]);  // pre-scaled by dinv[v]
    float hx = fmaxf(dv * (ax + self.x) + bias[2 * c], 0.0f);
    float hy = fmaxf(dv * (ay + self.y) + bias[2 * c + 1], 0.0f);
    if (FUSE_W3) {
        float pp = hx * W3[2 * c] + hy * W3[2 * c + 1];
#pragma unroll
        for (int off = 16; off; off >>= 1) pp += __shfl_xor(pp, off);
        if (lane == 0) ((float*)outv)[wave] = dv * pp;   // store pre-scaled t3'
    } else {
        if (lane < 32) ((__half2*)outv)[(size_t)wave * 32 + c] = __floats2half2_rn(hx, hy);
    }
}

// ---------------- layer 3 on pre-scaled t3': sigmoid(dv·(Σ w·t3'[s] + t3'[v]) + b3) ----
__global__ void k_agg3(const float* __restrict__ t3, const int* __restrict__ row_ptr,
                       const int2* __restrict__ edges, const float* __restrict__ dinv,
                       const float* __restrict__ b3, float* __restrict__ out, int n) {
    int v = blockIdx.x * blockDim.x + threadIdx.x;
    if (v >= n) return;
    float acc0 = t3[v];                        // self-loop, weight 1
    float acc1 = 0.0f;
    int beg = row_ptr[v], end = row_ptr[v + 1];
    int i = beg;
    for (; i + 8 <= end; i += 8) {
        int2 er[8]; float av[8];
#pragma unroll
        for (int j = 0; j < 8; j++) er[j] = ldnt2(&edges[i + j]);
#pragma unroll
        for (int j = 0; j < 8; j++) av[j] = t3[er[j].x];
#pragma unroll
        for (int j = 0; j < 8; j++) {
            if (j & 1) acc1 += __int_as_float(er[j].y) * av[j];
            else       acc0 += __int_as_float(er[j].y) * av[j];
        }
    }
    for (; i < end; i++) {
        int2 e = ldnt2(&edges[i]);
        acc0 += __int_as_float(e.y) * t3[e.x];
    }
    float z = dinv[v] * (acc0 + acc1) + b3[0];
    out[v] = 1.0f / (1.0f + expf(-z));
}

extern "C" void kernel_launch(void* const* d_in, const int* in_sizes, int n_in,
                              void* d_out, int out_size, void* d_ws, size_t ws_size,
                              hipStream_t stream) {
    const float* x  = (const float*)d_in[0];
    const int*   ei = (const int*)d_in[1];
    const float* w  = (const float*)d_in[2];
    const float* W1 = (const float*)d_in[3];
    const float* b1 = (const float*)d_in[4];
    const float* W2 = (const float*)d_in[5];
    const float* b2 = (const float*)d_in[6];
    const float* W3 = (const float*)d_in[7];
    const float* b3 = (const float*)d_in[8];
    float* out = (float*)d_out;

    const int N = NN, E = NE;
    const int* src = ei;
    const int* dst = ei + E;

    // workspace carve (256B aligned)
    char* p = (char*)d_ws;
    auto alloc = [&](size_t bytes) -> char* {
        char* r = p;
        p += (bytes + 255) & ~(size_t)255;
        return r;
    };
    float* dinv    = (float*)alloc((size_t)N * 4);
    int*   row_ptr = (int*)alloc((size_t)(N + 1) * 4);
    int*   binStart= (int*)alloc((NBIN + 1) * 4);
    int*   counts  = (int*)alloc((size_t)NBB * NBIN * 4);
    int2*  binned  = (int2*)alloc((size_t)E * 8);       // bin-ordered records
    int2*  edges   = (int2*)alloc((size_t)E * 8);       // compact CSR (src, raw w)
    __half* bufA   = (__half*)alloc((size_t)N * D * 2);
    __half* bufB   = (__half*)alloc((size_t)N * D * 2);
    float* t3      = (float*)alloc((size_t)N * 4);

    const int BT = 256;
    int gN = (N + BT - 1) / BT;
    int gW = (N * 64 + BT - 1) / BT;               // wave-per-node grids (4 waves/block)
    int nWaves = (N + 31) / 32;                    // gemm: wave per 32 rows
    int gG = (nWaves * 64 + BT - 1) / BT;

    // --- CSR build: zero global atomics, separate launches (each picks its own grid) ---
    k_binhist<<<NBB, BT, 0, stream>>>(dst, counts, E);
    k_binscan<<<1, 512, 0, stream>>>(counts, binStart);
    k_binscatter<<<NBB, BT, 0, stream>>>(src, dst, w, counts, binStart, binned, E);
    k_degcsr<<<NBIN, BT, 0, stream>>>(binned, binStart, dinv, row_ptr, edges, N);

    // --- layer 1 ---
    k_gemm<0><<<gG, BT, 0, stream>>>(x, W1, dinv, bufA, N);
    k_agg<0><<<gW, BT, 0, stream>>>((const __half2*)bufA, row_ptr, edges, dinv, b1, nullptr, bufB, N);
    // --- layer 2 (fused h2 @ W3 epilogue -> t3') ---
    k_gemm<1><<<gG, BT, 0, stream>>>(bufB, W2, dinv, bufA, N);
    k_agg<1><<<gW, BT, 0, stream>>>((const __half2*)bufA, row_ptr, edges, dinv, b2, W3, t3, N);
    // --- layer 3: scalar aggregation + bias + sigmoid ---
    k_agg3<<<gN, BT, 0, stream>>>(t3, row_ptr, edges, dinv, b3, out, N);
}

// Round 16
// 201.208 us; speedup vs baseline: 1.4615x; 1.0552x over previous
//
#include <hip/hip_runtime.h>
#include <hip/hip_fp16.h>
#include <math.h>

#define NN 100000
#define NE 1600000
#define D 64
#define BSH 8                         // bin = dst >> 8  (256 nodes/bin)
#define NBIN 391                      // ceil(100000/256)
#define EB 4096                       // edges per binning block
#define NBB ((NE + EB - 1) / EB)      // 391

typedef _Float16 f16x8 __attribute__((ext_vector_type(8)));
typedef float f32x4 __attribute__((ext_vector_type(4)));
typedef int   i32x4 __attribute__((ext_vector_type(4)));
typedef float fl32x4 __attribute__((ext_vector_type(4)));

__device__ __forceinline__ int2 ldnt2(const int2* p) {
    unsigned long long r = __builtin_nontemporal_load((const unsigned long long*)p);
    int2 o;
    o.x = (int)(unsigned)(r & 0xffffffffu);
    o.y = (int)(unsigned)(r >> 32);
    return o;
}

// ---------------- pass A: per-block bin histogram -> transposed counts[bin][blk] ----
__global__ void k_binhist(const int* __restrict__ dst, int* __restrict__ counts, int E) {
    __shared__ int h[NBIN];
    for (int i = threadIdx.x; i < NBIN; i += blockDim.x) h[i] = 0;
    __syncthreads();
    int e0 = blockIdx.x * EB;
    int e1 = min(e0 + EB, E);
    for (int e = e0 + (int)threadIdx.x * 4; e < e1; e += blockDim.x * 4) {
        i32x4 d4 = __builtin_nontemporal_load((const i32x4*)(dst + e));
        atomicAdd(&h[d4.x >> BSH], 1);
        atomicAdd(&h[d4.y >> BSH], 1);
        atomicAdd(&h[d4.z >> BSH], 1);
        atomicAdd(&h[d4.w >> BSH], 1);
    }
    __syncthreads();
    for (int i = threadIdx.x; i < NBIN; i += blockDim.x)
        counts[(size_t)i * NBB + blockIdx.x] = h[i];   // scattered 4B, L2-absorbed
}

// ---------------- parallel scan 1: block b scans its bin's NBB block-counts ----------
__global__ void k_binscan(int* __restrict__ counts, int* __restrict__ binTot) {
    __shared__ int sm[512];
    int b = blockIdx.x, t = threadIdx.x;
    int v0 = (t < NBB)       ? counts[(size_t)b * NBB + t] : 0;
    int v1 = (t + 256 < NBB) ? counts[(size_t)b * NBB + t + 256] : 0;
    sm[t] = v0; sm[t + 256] = v1;
    __syncthreads();
    for (int off = 1; off < 512; off <<= 1) {   // Hillis-Steele inclusive over 512
        int a0 = (t >= off) ? sm[t - off] : 0;
        int a1 = (t + 256 >= off) ? sm[t + 256 - off] : 0;
        __syncthreads();
        sm[t] += a0; sm[t + 256] += a1;
        __syncthreads();
    }
    if (t < NBB)       counts[(size_t)b * NBB + t] = sm[t] - v0;             // exclusive
    if (t + 256 < NBB) counts[(size_t)b * NBB + t + 256] = sm[t + 256] - v1;
    if (t == 0) binTot[b] = sm[511];
}

// ---------------- parallel scan 2: one block scans the NBIN bin totals ----------
__global__ void k_binscan2(const int* __restrict__ binTot, int* __restrict__ binStart) {
    __shared__ int sm[512];
    int t = threadIdx.x;
    int v = (t < NBIN) ? binTot[t] : 0;
    sm[t] = v;
    __syncthreads();
    for (int off = 1; off < 512; off <<= 1) {
        int add = (t >= off) ? sm[t - off] : 0;
        __syncthreads();
        sm[t] += add;
        __syncthreads();
    }
    if (t < NBIN) binStart[t] = sm[t] - v;       // exclusive bin base
    if (t == NBIN - 1) binStart[NBIN] = sm[t];   // == E
}

// ---------------- pass B: scatter edges into bin-contiguous order ----------------
__global__ void k_binscatter(const int* __restrict__ src, const int* __restrict__ dst,
                             const float* __restrict__ w, const int* __restrict__ counts,
                             const int* __restrict__ binStart, int2* __restrict__ binned,
                             int E) {
    __shared__ int cur[NBIN];
    for (int i = threadIdx.x; i < NBIN; i += blockDim.x)
        cur[i] = binStart[i] + counts[(size_t)i * NBB + blockIdx.x];  // L2-hot
    __syncthreads();
    int e0 = blockIdx.x * EB;
    int e1 = min(e0 + EB, E);
    for (int e = e0 + (int)threadIdx.x * 4; e < e1; e += blockDim.x * 4) {
        i32x4  d4 = __builtin_nontemporal_load((const i32x4*)(dst + e));
        i32x4  s4 = __builtin_nontemporal_load((const i32x4*)(src + e));
        fl32x4 w4 = __builtin_nontemporal_load((const fl32x4*)(w + e));
        int pos;
        pos = atomicAdd(&cur[d4.x >> BSH], 1);
        binned[pos] = make_int2(((d4.x & 255) << 17) | s4.x, __float_as_int(w4.x));
        pos = atomicAdd(&cur[d4.y >> BSH], 1);
        binned[pos] = make_int2(((d4.y & 255) << 17) | s4.y, __float_as_int(w4.y));
        pos = atomicAdd(&cur[d4.z >> BSH], 1);
        binned[pos] = make_int2(((d4.z & 255) << 17) | s4.z, __float_as_int(w4.z));
        pos = atomicAdd(&cur[d4.w >> BSH], 1);
        binned[pos] = make_int2(((d4.w & 255) << 17) | s4.w, __float_as_int(w4.w));
    }
}

// ---------------- fused deg + CSR: dinv/row_ptr (pass 1) + rank/copy (pass 2) ------
// Edge record = (src, raw w bits): dinv factors are applied in gemm (src side)
// and in the agg epilogue (dst side, hoisted out of the row sum).
__global__ void k_degcsr(const int2* __restrict__ binned, const int* __restrict__ binStart,
                         float* __restrict__ dinv, int* __restrict__ row_ptr,
                         int2* __restrict__ edges, int n) {
    __shared__ int   cnt[256];
    __shared__ float ws[256];
    __shared__ int   off[256];
    __shared__ int   rp[256];
    int b = blockIdx.x, t = threadIdx.x;
    cnt[t] = 0; ws[t] = 0.0f;
    __syncthreads();
    int e0 = binStart[b], e1 = binStart[b + 1];
    for (int e = e0 + t; e < e1; e += 256) {
        int2 r = binned[e];
        int dlow = (unsigned)r.x >> 17;
        atomicAdd(&cnt[dlow], 1);
        atomicAdd(&ws[dlow], __int_as_float(r.y));
    }
    __syncthreads();
    int v = cnt[t];
    off[t] = v;
    __syncthreads();
    for (int o = 1; o < 256; o <<= 1) {
        int add = (t >= o) ? off[t - o] : 0;
        __syncthreads();
        off[t] += add;
        __syncthreads();
    }
    int node = b * 256 + t;
    rp[t] = e0 + off[t] - v;                 // exclusive row base
    if (node < n) {
        dinv[node] = rsqrtf(1.0f + ws[t]);   // self-loop weight 1
        row_ptr[node] = rp[t];
    }
    if (b == NBIN - 1 && t == 0) row_ptr[n] = binStart[NBIN];
    cnt[t] = 0;                              // reuse as rank cursor
    __syncthreads();
    for (int e = e0 + t; e < e1; e += 256) { // pass 2: bin is L2-hot, pure rank+copy
        int2 r = binned[e];
        int dlow = (unsigned)r.x >> 17;
        int rank = atomicAdd(&cnt[dlow], 1);
        edges[rp[dlow] + rank] = make_int2(r.x & 0x1FFFF, r.y);
    }
}

// ---------------- dense: T' = dinv ⊙ (X @ W) via MFMA 16x16x32 f16 ----------------
// Wave computes 32 rows (2 tiles of 16). A/B frag: lane&15 = row/col,
// 8 contiguous k at (lane>>4)*8. C/D: col=lane&15, row=(lane>>4)*4+reg.
template <int IN_HALF>
__global__ void k_gemm(const void* __restrict__ Xv, const float* __restrict__ W,
                       const float* __restrict__ dinv, __half* __restrict__ T, int n) {
    int wid = (int)((blockIdx.x * blockDim.x + threadIdx.x) >> 6);
    int lane = threadIdx.x & 63;
    int col16 = lane & 15, kg = lane >> 4;
    int r0 = wid * 32;
    if (r0 >= n) return;
    // B fragments: bf[kk][ct], elem j = W[kk*32 + kg*8 + j][ct*16 + col16]
    f16x8 bf[2][4];
#pragma unroll
    for (int kk = 0; kk < 2; kk++)
#pragma unroll
        for (int ct = 0; ct < 4; ct++) {
            f16x8 b;
#pragma unroll
            for (int j = 0; j < 8; j++)
                b[j] = (_Float16)W[(size_t)(kk * 32 + kg * 8 + j) * D + ct * 16 + col16];
            bf[kk][ct] = b;
        }
#pragma unroll
    for (int tt = 0; tt < 2; tt++) {
        int row = r0 + tt * 16 + col16;           // this lane's A row
        f16x8 a0, a1;
        if (IN_HALF) {
            const _Float16* xr = (const _Float16*)Xv + (size_t)row * D;
            a0 = *(const f16x8*)(xr + kg * 8);
            a1 = *(const f16x8*)(xr + 32 + kg * 8);
        } else {
            const float* xr = (const float*)Xv + (size_t)row * D;
#pragma unroll
            for (int j = 0; j < 8; j++) {
                a0[j] = (_Float16)xr[kg * 8 + j];
                a1[j] = (_Float16)xr[32 + kg * 8 + j];
            }
        }
        float dvr[4];
#pragma unroll
        for (int r = 0; r < 4; r++) dvr[r] = dinv[r0 + tt * 16 + kg * 4 + r];
#pragma unroll
        for (int ct = 0; ct < 4; ct++) {
            f32x4 z = {0.0f, 0.0f, 0.0f, 0.0f};
            z = __builtin_amdgcn_mfma_f32_16x16x32_f16(a0, bf[0][ct], z, 0, 0, 0);
            z = __builtin_amdgcn_mfma_f32_16x16x32_f16(a1, bf[1][ct], z, 0, 0, 0);
            __half* to = T + (size_t)(r0 + tt * 16 + kg * 4) * D + ct * 16 + col16;
#pragma unroll
            for (int r = 0; r < 4; r++)
                to[(size_t)r * D] = __float2half(z[r] * dvr[r]);
        }
    }
}

// ---------------- aggregation on pre-scaled fp16 rows (round-11 proven form) --------
// acc = Σ w_e·T'[s] + T'[v]  (self-loop weight 1); out = relu(dv·acc + b).
// Tiers 16/8/4/2 edges (ILP 8/4/2/1 per half-wave) + odd tail; NT edge loads.
template <int FUSE_W3>
__global__ void k_agg(const __half2* __restrict__ T2, const int* __restrict__ row_ptr,
                      const int2* __restrict__ edges, const float* __restrict__ dinv,
                      const float* __restrict__ bias, const float* __restrict__ W3,
                      void* __restrict__ outv, int n) {
    int wave = (int)((blockIdx.x * blockDim.x + threadIdx.x) >> 6);
    int lane = threadIdx.x & 63;
    if (wave >= n) return;
    int c = lane & 31;
    int h = lane >> 5;
    int beg = row_ptr[wave], end = row_ptr[wave + 1];
    float ax = 0.0f, ay = 0.0f, bx = 0.0f, by = 0.0f;
    int i = beg;
    for (; i + 16 <= end; i += 16) {
        int2 er[8];
#pragma unroll
        for (int j = 0; j < 8; j++) er[j] = ldnt2(&edges[i + 2 * j + h]);
        __half2 tv[8];
#pragma unroll
        for (int j = 0; j < 8; j++) tv[j] = T2[(size_t)er[j].x * 32 + c];
#pragma unroll
        for (int j = 0; j < 8; j++) {
            float nv = __int_as_float(er[j].y);
            float2 f = __half22float2(tv[j]);
            if (j & 1) { bx += nv * f.x; by += nv * f.y; }
            else       { ax += nv * f.x; ay += nv * f.y; }
        }
    }
    if (i + 8 <= end) {
        int2 er[4];
#pragma unroll
        for (int j = 0; j < 4; j++) er[j] = ldnt2(&edges[i + 2 * j + h]);
        __half2 tv[4];
#pragma unroll
        for (int j = 0; j < 4; j++) tv[j] = T2[(size_t)er[j].x * 32 + c];
#pragma unroll
        for (int j = 0; j < 4; j++) {
            float nv = __int_as_float(er[j].y);
            float2 f = __half22float2(tv[j]);
            if (j & 1) { bx += nv * f.x; by += nv * f.y; }
            else       { ax += nv * f.x; ay += nv * f.y; }
        }
        i += 8;
    }
    if (i + 4 <= end) {
        int2 er[2];
#pragma unroll
        for (int j = 0; j < 2; j++) er[j] = ldnt2(&edges[i + 2 * j + h]);
#pragma unroll
        for (int j = 0; j < 2; j++) {
            float nv = __int_as_float(er[j].y);
            float2 f = __half22float2(T2[(size_t)er[j].x * 32 + c]);
            if (j & 1) { bx += nv * f.x; by += nv * f.y; }
            else       { ax += nv * f.x; ay += nv * f.y; }
        }
        i += 4;
    }
    if (i + 2 <= end) {
        int2 e = ldnt2(&edges[i + h]);
        float nv = __int_as_float(e.y);
        float2 f = __half22float2(T2[(size_t)e.x * 32 + c]);
        ax += nv * f.x; ay += nv * f.y;
        i += 2;
    }
    if (i < end && h == 0) {                       // odd leftover: half 0 only
        int2 e = ldnt2(&edges[i]);
        float nv = __int_as_float(e.y);
        float2 f = __half22float2(T2[(size_t)e.x * 32 + c]);
        ax += nv * f.x; ay += nv * f.y;
    }
    ax += bx; ay += by;
    ax += __shfl_xor(ax, 32);                      // combine halves
    ay += __shfl_xor(ay, 32);
    float dv = dinv[wave];
    float2 self = __half22float2(T2[(size_t)wave * 32 + c]);  // pre-scaled by dinv[v]
    float hx = fmaxf(dv * (ax + self.x) + bias[2 * c], 0.0f);
    float hy = fmaxf(dv * (ay + self.y) + bias[2 * c + 1], 0.0f);
    if (FUSE_W3) {
        float pp = hx * W3[2 * c] + hy * W3[2 * c + 1];
#pragma unroll
        for (int off = 16; off; off >>= 1) pp += __shfl_xor(pp, off);
        if (lane == 0) ((float*)outv)[wave] = dv * pp;   // store pre-scaled t3'
    } else {
        if (lane < 32) ((__half2*)outv)[(size_t)wave * 32 + c] = __floats2half2_rn(hx, hy);
    }
}

// ---------------- layer 3 on pre-scaled t3': sigmoid(dv·(Σ w·t3'[s] + t3'[v]) + b3) ----
__global__ void k_agg3(const float* __restrict__ t3, const int* __restrict__ row_ptr,
                       const int2* __restrict__ edges, const float* __restrict__ dinv,
                       const float* __restrict__ b3, float* __restrict__ out, int n) {
    int v = blockIdx.x * blockDim.x + threadIdx.x;
    if (v >= n) return;
    float acc0 = t3[v];                        // self-loop, weight 1
    float acc1 = 0.0f;
    int beg = row_ptr[v], end = row_ptr[v + 1];
    int i = beg;
    for (; i + 8 <= end; i += 8) {
        int2 er[8]; float av[8];
#pragma unroll
        for (int j = 0; j < 8; j++) er[j] = ldnt2(&edges[i + j]);
#pragma unroll
        for (int j = 0; j < 8; j++) av[j] = t3[er[j].x];
#pragma unroll
        for (int j = 0; j < 8; j++) {
            if (j & 1) acc1 += __int_as_float(er[j].y) * av[j];
            else       acc0 += __int_as_float(er[j].y) * av[j];
        }
    }
    for (; i < end; i++) {
        int2 e = ldnt2(&edges[i]);
        acc0 += __int_as_float(e.y) * t3[e.x];
    }
    float z = dinv[v] * (acc0 + acc1) + b3[0];
    out[v] = 1.0f / (1.0f + expf(-z));
}

extern "C" void kernel_launch(void* const* d_in, const int* in_sizes, int n_in,
                              void* d_out, int out_size, void* d_ws, size_t ws_size,
                              hipStream_t stream) {
    const float* x  = (const float*)d_in[0];
    const int*   ei = (const int*)d_in[1];
    const float* w  = (const float*)d_in[2];
    const float* W1 = (const float*)d_in[3];
    const float* b1 = (const float*)d_in[4];
    const float* W2 = (const float*)d_in[5];
    const float* b2 = (const float*)d_in[6];
    const float* W3 = (const float*)d_in[7];
    const float* b3 = (const float*)d_in[8];
    float* out = (float*)d_out;

    const int N = NN, E = NE;
    const int* src = ei;
    const int* dst = ei + E;

    // workspace carve (256B aligned)
    char* p = (char*)d_ws;
    auto alloc = [&](size_t bytes) -> char* {
        char* r = p;
        p += (bytes + 255) & ~(size_t)255;
        return r;
    };
    float* dinv    = (float*)alloc((size_t)N * 4);
    int*   row_ptr = (int*)alloc((size_t)(N + 1) * 4);
    int*   binStart= (int*)alloc((NBIN + 1) * 4);
    int*   binTot  = (int*)alloc(NBIN * 4);
    int*   counts  = (int*)alloc((size_t)NBB * NBIN * 4);
    int2*  binned  = (int2*)alloc((size_t)E * 8);       // bin-ordered records
    int2*  edges   = (int2*)alloc((size_t)E * 8);       // compact CSR (src, raw w)
    __half* bufA   = (__half*)alloc((size_t)N * D * 2);
    __half* bufB   = (__half*)alloc((size_t)N * D * 2);
    float* t3      = (float*)alloc((size_t)N * 4);

    const int BT = 256;
    int gN = (N + BT - 1) / BT;
    int gW = (N * 64 + BT - 1) / BT;               // wave-per-node grids (4 waves/block)
    int nWaves = (N + 31) / 32;                    // gemm: wave per 32 rows
    int gG = (nWaves * 64 + BT - 1) / BT;

    // --- CSR build: zero global atomics, parallel scans ---
    k_binhist<<<NBB, BT, 0, stream>>>(dst, counts, E);
    k_binscan<<<NBIN, BT, 0, stream>>>(counts, binTot);
    k_binscan2<<<1, 512, 0, stream>>>(binTot, binStart);
    k_binscatter<<<NBB, BT, 0, stream>>>(src, dst, w, counts, binStart, binned, E);
    k_degcsr<<<NBIN, BT, 0, stream>>>(binned, binStart, dinv, row_ptr, edges, N);

    // --- layer 1 ---
    k_gemm<0><<<gG, BT, 0, stream>>>(x, W1, dinv, bufA, N);
    k_agg<0><<<gW, BT, 0, stream>>>((const __half2*)bufA, row_ptr, edges, dinv, b1, nullptr, bufB, N);
    // --- layer 2 (fused h2 @ W3 epilogue -> t3') ---
    k_gemm<1><<<gG, BT, 0, stream>>>(bufB, W2, dinv, bufA, N);
    k_agg<1><<<gW, BT, 0, stream>>>((const __half2*)bufA, row_ptr, edges, dinv, b2, W3, t3, N);
    // --- layer 3: scalar aggregation + bias + sigmoid ---
    k_agg3<<<gN, BT, 0, stream>>>(t3, row_ptr, edges, dinv, b3, out, N);
}